// Round 1
// baseline (417.023 us; speedup 1.0000x reference)
//
#include <hip/hip_runtime.h>

#define TT   256
#define HID  30
#define NG   120
#define LOG2E 1.4426950408889634f

typedef __bf16 bf16x8_t __attribute__((ext_vector_type(8)));
typedef float  f32x4_t  __attribute__((ext_vector_type(4)));

__device__ __forceinline__ float fexp2(float x){
#if __has_builtin(__builtin_amdgcn_exp2f)
    return __builtin_amdgcn_exp2f(x);
#else
    return exp2f(x);
#endif
}
__device__ __forceinline__ float frcp(float x){
#if __has_builtin(__builtin_amdgcn_rcpf)
    return __builtin_amdgcn_rcpf(x);
#else
    return 1.f/x;
#endif
}
__device__ __forceinline__ float fsigmoid(float x){
    return frcp(1.f + fexp2(-LOG2E * x));
}
__device__ __forceinline__ float ftanh_f(float x){
    return 2.f*frcp(1.f + fexp2(-2.f*LOG2E*x)) - 1.f;
}

// Block = 512 threads = 8 waves, owns 16 batch rows for all T steps.
// Wave w owns gate columns [16w, 16w+16) of both layers; weights resident as
// B-fragments in VGPRs. h0/h1 exchanged via LDS in A-frag layout (bf16,
// row-pad 40 -> bank stride 20 -> only 2-way conflicts, free).
__global__ __launch_bounds__(512, 4)
void lstm_fused(const float* __restrict__ x,
    const float* __restrict__ Wih0, const float* __restrict__ Whh0,
    const float* __restrict__ bih0, const float* __restrict__ bhh0,
    const float* __restrict__ Wih1, const float* __restrict__ Whh1,
    const float* __restrict__ bih1, const float* __restrict__ bhh1,
    const float* __restrict__ Wfc1, const float* __restrict__ bfc1,
    const float* __restrict__ Wfc2, const float* __restrict__ bfc2,
    const float* __restrict__ Wfc3, const float* __restrict__ bfc3,
    float* __restrict__ out)
{
    __shared__ float  sgA[128*20];     // activated gates layer0, [col][m] pad 20
    __shared__ float  sgB[128*20];     // activated gates layer1
    __shared__ __bf16 h0f[16*40];      // h0 in A-frag layout [m][k], pad 40
    __shared__ __bf16 h1f[16*40];
    __shared__ float  h1_last[16*32];  // final h1 fp32 for FC head
    __shared__ float  zbuf[16*64];
    __shared__ float  z2buf[16*32];

    const int tid  = threadIdx.x;
    const int lane = tid & 63;
    const int wv   = tid >> 6;       // wave id = gate tile id (0..7)
    const int ln15 = lane & 15;
    const int q    = lane >> 4;      // quad 0..3
    const int col  = wv*16 + ln15;   // gate column 0..127 (>=120 is pad)
    const int bbase = blockIdx.x * 16;

    // ---- resident B-fragments: B[k=(q*8+j)][n=ln15] = W[col][k] (bf16) ----
    bf16x8_t fw_hh0{}, fw_ih1{}, fw_hh1{};
    #pragma unroll
    for (int j = 0; j < 8; ++j) {
        int k = q*8 + j;
        float a = 0.f, b = 0.f, c = 0.f;
        if (col < NG && k < HID) {
            a = Whh0[col*HID + k];
            b = Wih1[col*HID + k];
            c = Whh1[col*HID + k];
        }
        fw_hh0[j] = (__bf16)a;
        fw_ih1[j] = (__bf16)b;
        fw_hh1[j] = (__bf16)c;
    }
    // layer0 input weights (3 per column) + combined biases
    float wx0=0.f, wx1=0.f, wx2=0.f, bias0=0.f, bias1=0.f;
    if (col < NG) {
        wx0 = Wih0[col*3+0]; wx1 = Wih0[col*3+1]; wx2 = Wih0[col*3+2];
        bias0 = bih0[col] + bhh0[col];
        bias1 = bih1[col] + bhh1[col];
    }
    // activation type per column: 0:i 1:f sigmoid, 2:g tanh, 3:o sigmoid
    const bool isg = (col < NG) && (col / HID == 2);
    const float mco = isg ? (-2.f*LOG2E) : (-LOG2E);
    const float aco = isg ? 2.f : 1.f;
    const float bco = isg ? -1.f : 0.f;

    // state-update ownership: thread -> (hidden index sk, batch row sm)
    const int sm = tid & 15;
    const int sk = tid >> 4;         // valid when < 30
    float c0 = 0.f, c1 = 0.f;

    for (int i = tid; i < 16*40; i += 512) { h0f[i] = (__bf16)0.f; h1f[i] = (__bf16)0.f; }
    __syncthreads();

    const float* xbase0 = x + (bbase + q*4) * (TT*3);

    #pragma unroll 1
    for (int t = 0; t < TT; ++t) {
        // ---- phase 1: gates0 = bias0 + x_t @ Wih0^T + h0 @ Whh0^T ----
        f32x4_t acc = {bias0, bias0, bias0, bias0};
        #pragma unroll
        for (int r = 0; r < 4; ++r) {
            const float* xp = xbase0 + r*(TT*3) + t*3;
            acc[r] += xp[0]*wx0 + xp[1]*wx1 + xp[2]*wx2;
        }
        bf16x8_t a0 = *(const bf16x8_t*)(h0f + ln15*40 + q*8);
        acc = __builtin_amdgcn_mfma_f32_16x16x32_bf16(a0, fw_hh0, acc, 0, 0, 0);
        f32x4_t ga;
        #pragma unroll
        for (int r = 0; r < 4; ++r)
            ga[r] = aco*frcp(1.f + fexp2(acc[r]*mco)) + bco;   // sigmoid or tanh
        *(f32x4_t*)(sgA + col*20 + q*4) = ga;                  // [col][m=q*4+r]
        __syncthreads();

        // ---- phase 2: c0/h0 update ----
        if (sk < HID) {
            float gi = sgA[(sk        )*20 + sm];
            float gf = sgA[(sk +   HID)*20 + sm];
            float gg = sgA[(sk + 2*HID)*20 + sm];
            float go = sgA[(sk + 3*HID)*20 + sm];
            c0 = gf*c0 + gi*gg;
            h0f[sm*40 + sk] = (__bf16)(go * ftanh_f(c0));
        }
        __syncthreads();

        // ---- phase 3: gates1 = bias1 + h0_new @ Wih1^T + h1 @ Whh1^T ----
        f32x4_t acc2 = {bias1, bias1, bias1, bias1};
        bf16x8_t a1 = *(const bf16x8_t*)(h0f + ln15*40 + q*8);
        bf16x8_t a2 = *(const bf16x8_t*)(h1f + ln15*40 + q*8);
        acc2 = __builtin_amdgcn_mfma_f32_16x16x32_bf16(a1, fw_ih1, acc2, 0, 0, 0);
        acc2 = __builtin_amdgcn_mfma_f32_16x16x32_bf16(a2, fw_hh1, acc2, 0, 0, 0);
        #pragma unroll
        for (int r = 0; r < 4; ++r)
            ga[r] = aco*frcp(1.f + fexp2(acc2[r]*mco)) + bco;
        *(f32x4_t*)(sgB + col*20 + q*4) = ga;
        __syncthreads();

        // ---- phase 4: c1/h1 update (no barrier: next phase1 touches only sgA/h0f,
        //      both ordered by >=2 earlier barriers) ----
        if (sk < HID) {
            float gi = sgB[(sk        )*20 + sm];
            float gf = sgB[(sk +   HID)*20 + sm];
            float gg = sgB[(sk + 2*HID)*20 + sm];
            float go = sgB[(sk + 3*HID)*20 + sm];
            c1 = gf*c1 + gi*gg;
            float h1v = go * ftanh_f(c1);
            h1f[sm*40 + sk] = (__bf16)h1v;
            if (t == TT-1) h1_last[sm*32 + sk] = h1v;
        }
    }
    __syncthreads();

    // ---- FC head (fp32, trivial cost) ----
    #pragma unroll
    for (int rep = 0; rep < 2; ++rep) {
        int idx = tid + rep*512;          // 16*64 = 1024 outputs
        int m = idx >> 6, u = idx & 63;
        float a = bfc1[u];
        for (int k = 0; k < HID; ++k) a += h1_last[m*32+k] * Wfc1[u*HID+k];
        zbuf[m*64+u] = fmaxf(a, 0.f);
    }
    __syncthreads();
    {
        int m = tid >> 5, v = tid & 31;   // 16*32 = 512 outputs
        float a = bfc2[v];
        for (int u = 0; u < 64; ++u) a += zbuf[m*64+u] * Wfc2[v*64+u];
        z2buf[m*32+v] = fmaxf(a, 0.f);
    }
    __syncthreads();
    if (tid < 16) {
        float a = bfc3[0];
        for (int v = 0; v < 32; ++v) a += z2buf[tid*32+v] * Wfc3[v];
        out[bbase + tid] = fsigmoid(a);
    }
}

extern "C" void kernel_launch(void* const* d_in, const int* in_sizes, int n_in,
                              void* d_out, int out_size, void* d_ws, size_t ws_size,
                              hipStream_t stream) {
    const float* x    = (const float*)d_in[0];
    const float* Wih0 = (const float*)d_in[1];
    const float* Whh0 = (const float*)d_in[2];
    const float* bih0 = (const float*)d_in[3];
    const float* bhh0 = (const float*)d_in[4];
    const float* Wih1 = (const float*)d_in[5];
    const float* Whh1 = (const float*)d_in[6];
    const float* bih1 = (const float*)d_in[7];
    const float* bhh1 = (const float*)d_in[8];
    const float* Wfc1 = (const float*)d_in[9];
    const float* bfc1 = (const float*)d_in[10];
    const float* Wfc2 = (const float*)d_in[11];
    const float* bfc2 = (const float*)d_in[12];
    const float* Wfc3 = (const float*)d_in[13];
    const float* bfc3 = (const float*)d_in[14];
    float* outp = (float*)d_out;

    hipLaunchKernelGGL(lstm_fused, dim3(512), dim3(512), 0, stream,
        x, Wih0, Whh0, bih0, bhh0, Wih1, Whh1, bih1, bhh1,
        Wfc1, bfc1, Wfc2, bfc2, Wfc3, bfc3, outp);
}

// Round 2
// 408.516 us; speedup vs baseline: 1.0208x; 1.0208x over previous
//
#include <hip/hip_runtime.h>

#define TT   256
#define HID  30
#define LOG2E 1.4426950408889634f

typedef __bf16 bf16x8_t __attribute__((ext_vector_type(8)));
typedef float  f32x4_t  __attribute__((ext_vector_type(4)));

__device__ __forceinline__ float fexp2(float x){
#if __has_builtin(__builtin_amdgcn_exp2f)
    return __builtin_amdgcn_exp2f(x);
#else
    return exp2f(x);
#endif
}
__device__ __forceinline__ float frcp(float x){
#if __has_builtin(__builtin_amdgcn_rcpf)
    return __builtin_amdgcn_rcpf(x);
#else
    return 1.f/x;
#endif
}
__device__ __forceinline__ float fsigmoid(float x){ return frcp(1.f + fexp2(-LOG2E*x)); }
__device__ __forceinline__ float ftanh_f(float x){ return 2.f*frcp(1.f + fexp2(-2.f*LOG2E*x)) - 1.f; }

// Block = 256 threads = 4 waves, owns 16 batch rows for all T steps.
// Wave w owns hidden quarter [8w, 8w+8) of BOTH layers, packed as two
// 16-col MFMA tiles: tile0 = {i|f} x 8 units, tile1 = {g|o} x 8 units
// (cols 0..7 = first gate, 8..15 = second gate). Thus all 4 gates of a
// hidden unit live in lanes n and n^8 of the SAME wave: one shfl_xor(8)
// of (i*g) replaces the old block-wide gate exchange. Only h (16x30 bf16,
// double-buffered, +x0/x1 in k-slots 30/31) crosses waves: 2 barriers/step.
__global__ __launch_bounds__(256, 2)
void lstm_fused(const float* __restrict__ x,
    const float* __restrict__ Wih0, const float* __restrict__ Whh0,
    const float* __restrict__ bih0, const float* __restrict__ bhh0,
    const float* __restrict__ Wih1, const float* __restrict__ Whh1,
    const float* __restrict__ bih1, const float* __restrict__ bhh1,
    const float* __restrict__ Wfc1, const float* __restrict__ bfc1,
    const float* __restrict__ Wfc2, const float* __restrict__ bfc2,
    const float* __restrict__ Wfc3, const float* __restrict__ bfc3,
    float* __restrict__ out)
{
    __shared__ __bf16 h0f[2][16][32];   // [buf][row m][k]; k=30,31 hold x0,x1(t)
    __shared__ __bf16 h1f[2][16][32];   // k=30,31 stay 0
    __shared__ float  h1_last[16*32];
    __shared__ float  zbuf[16*64];
    __shared__ float  z2buf[16*32];

    const int tid  = threadIdx.x;
    const int lane = tid & 63;
    const int wv   = tid >> 6;        // hidden quarter 0..3
    const int n    = lane & 15;       // tile col
    const int q    = lane >> 4;       // quad (C/D row group, A/B k group)
    const int nl   = n & 7;
    const int u    = wv*8 + nl;       // hidden unit this lane pairs on
    const int hi   = n >> 3;          // 0: {i,g} side, 1: {f,o} side
    const bool colok = (u < HID);
    const int bbase = blockIdx.x * 16;

    // weight rows: tile0 gate = i/f, tile1 gate = g/o  (PyTorch order i,f,g,o)
    const int uq  = colok ? u : 0;
    const int wr0 = (hi ? 1 : 0)*HID + uq;
    const int wr1 = (hi ? 3 : 2)*HID + uq;

    // ---- resident B-fragments: B[k=(q*8+j)][n] ----
    bf16x8_t fb0_hh0{}, fb1_hh0{}, fb0_ih1{}, fb1_ih1{}, fb0_hh1{}, fb1_hh1{};
    #pragma unroll
    for (int j = 0; j < 8; ++j) {
        int k = q*8 + j;
        float v00=0.f, v01=0.f, v10=0.f, v11=0.f, v20=0.f, v21=0.f;
        if (colok) {
            if (k < HID) {
                v00 = Whh0[wr0*HID + k];  v01 = Whh0[wr1*HID + k];
                v10 = Wih1[wr0*HID + k];  v11 = Wih1[wr1*HID + k];
                v20 = Whh1[wr0*HID + k];  v21 = Whh1[wr1*HID + k];
            } else {            // k = 30,31 -> x0,x1 columns of Wih0 (layer 0 only)
                int xi = k - HID;
                v00 = Wih0[wr0*3 + xi];  v01 = Wih0[wr1*3 + xi];
            }
        }
        fb0_hh0[j]=(__bf16)v00; fb1_hh0[j]=(__bf16)v01;
        fb0_ih1[j]=(__bf16)v10; fb1_ih1[j]=(__bf16)v11;
        fb0_hh1[j]=(__bf16)v20; fb1_hh1[j]=(__bf16)v21;
    }
    float bias00=0.f, bias01=0.f, bias10=0.f, bias11=0.f, wx20=0.f, wx21=0.f;
    if (colok) {
        bias00 = bih0[wr0] + bhh0[wr0];  bias01 = bih0[wr1] + bhh0[wr1];
        bias10 = bih1[wr0] + bhh1[wr0];  bias11 = bih1[wr1] + bhh1[wr1];
        wx20 = Wih0[wr0*3 + 2];          wx21 = Wih0[wr1*3 + 2];
    }
    // tile1 activation: cols 0..7 = g (tanh), 8..15 = o (sigmoid)
    const float mco1 = (hi==0) ? (-2.f*LOG2E) : (-LOG2E);
    const float aco1 = (hi==0) ? 2.f : 1.f;
    const float bco1 = (hi==0) ? -1.f : 0.f;

    f32x4_t c0 = {0.f,0.f,0.f,0.f}, c1 = {0.f,0.f,0.f,0.f};

    for (int i = tid; i < 2*16*32; i += 256) {
        (&h0f[0][0][0])[i] = (__bf16)0.f;
        (&h1f[0][0][0])[i] = (__bf16)0.f;
    }
    __syncthreads();
    if (tid < 16) {               // x0,x1 for t=0 into read-buffer 0
        float xa = x[(size_t)(bbase+tid)*TT*3 + 0];
        float xb = x[(size_t)(bbase+tid)*TT*3 + 1];
        h0f[0][tid][30] = (__bf16)xa;
        h0f[0][tid][31] = (__bf16)xb;
    }
    __syncthreads();

    // x2 prefetch for t=0 (rows q*4+r; same addr across the 16 lanes of a quad)
    f32x4_t x2;
    #pragma unroll
    for (int r = 0; r < 4; ++r)
        x2[r] = x[(size_t)(bbase + q*4 + r)*TT*3 + 2];

    #pragma unroll 1
    for (int t = 0; t < TT; ++t) {
        const int rb = t & 1, wb = rb ^ 1;

        // ---- layer 0: gates = bias + x@Wih0 + h0@Whh0 (x0,x1 inside A-frag) ----
        bf16x8_t A0 = *(const bf16x8_t*)(&h0f[rb][n][q*8]);
        f32x4_t acc0 = {bias00,bias00,bias00,bias00};
        f32x4_t acc1 = {bias01,bias01,bias01,bias01};
        #pragma unroll
        for (int r = 0; r < 4; ++r) { acc0[r] += x2[r]*wx20; acc1[r] += x2[r]*wx21; }
        acc0 = __builtin_amdgcn_mfma_f32_16x16x32_bf16(A0, fb0_hh0, acc0, 0,0,0);
        acc1 = __builtin_amdgcn_mfma_f32_16x16x32_bf16(A0, fb1_hh0, acc1, 0,0,0);

        // prefetch x(t+1)
        const int tt = (t+1 < TT) ? (t+1) : (TT-1);
        f32x4_t x2n;
        #pragma unroll
        for (int r = 0; r < 4; ++r)
            x2n[r] = x[(size_t)(bbase + q*4 + r)*TT*3 + tt*3 + 2];
        if (tid < 16) {            // x0,x1(t+1) into write-buffer
            float xa = x[(size_t)(bbase+tid)*TT*3 + tt*3 + 0];
            float xb = x[(size_t)(bbase+tid)*TT*3 + tt*3 + 1];
            h0f[wb][tid][30] = (__bf16)xa;
            h0f[wb][tid][31] = (__bf16)xb;
        }

        f32x4_t ga0, ga1, p;
        #pragma unroll
        for (int r = 0; r < 4; ++r) {
            ga0[r] = frcp(1.f + fexp2(acc0[r]*(-LOG2E)));          // i | f
            ga1[r] = aco1*frcp(1.f + fexp2(acc1[r]*mco1)) + bco1;  // g | o
            p[r]   = ga0[r]*ga1[r];                                // i*g on hi==0
        }
        #pragma unroll
        for (int r = 0; r < 4; ++r) p[r] = __shfl_xor(p[r], 8, 64);
        #pragma unroll
        for (int r = 0; r < 4; ++r) c0[r] = ga0[r]*c0[r] + p[r];   // f*c + i*g (hi==1)
        if (hi && colok) {
            #pragma unroll
            for (int r = 0; r < 4; ++r)
                h0f[wb][q*4+r][u] = (__bf16)(ga1[r]*ftanh_f(c0[r]));  // o*tanh(c)
        }
        __syncthreads();   // B1: h0(t) + x(t+1) visible

        // ---- layer 1: gates = bias + h0(t)@Wih1 + h1(t-1)@Whh1 ----
        bf16x8_t A1 = *(const bf16x8_t*)(&h0f[wb][n][q*8]);
        bf16x8_t A2 = *(const bf16x8_t*)(&h1f[rb][n][q*8]);
        f32x4_t d0 = {bias10,bias10,bias10,bias10};
        f32x4_t d1 = {bias11,bias11,bias11,bias11};
        d0 = __builtin_amdgcn_mfma_f32_16x16x32_bf16(A1, fb0_ih1, d0, 0,0,0);
        d0 = __builtin_amdgcn_mfma_f32_16x16x32_bf16(A2, fb0_hh1, d0, 0,0,0);
        d1 = __builtin_amdgcn_mfma_f32_16x16x32_bf16(A1, fb1_ih1, d1, 0,0,0);
        d1 = __builtin_amdgcn_mfma_f32_16x16x32_bf16(A2, fb1_hh1, d1, 0,0,0);
        #pragma unroll
        for (int r = 0; r < 4; ++r) {
            ga0[r] = frcp(1.f + fexp2(d0[r]*(-LOG2E)));
            ga1[r] = aco1*frcp(1.f + fexp2(d1[r]*mco1)) + bco1;
            p[r]   = ga0[r]*ga1[r];
        }
        #pragma unroll
        for (int r = 0; r < 4; ++r) p[r] = __shfl_xor(p[r], 8, 64);
        #pragma unroll
        for (int r = 0; r < 4; ++r) c1[r] = ga0[r]*c1[r] + p[r];
        if (hi && colok) {
            #pragma unroll
            for (int r = 0; r < 4; ++r) {
                float h1v = ga1[r]*ftanh_f(c1[r]);
                h1f[wb][q*4+r][u] = (__bf16)h1v;
                if (t == TT-1) h1_last[(q*4+r)*32 + u] = h1v;
            }
        }
        x2 = x2n;
        __syncthreads();   // B2: h1(t) visible; h0f[rb] safe to overwrite next iter
    }

    // ---- FC head ----
    #pragma unroll
    for (int rep = 0; rep < 4; ++rep) {
        int idx = tid + rep*256;          // 16*64
        int m = idx >> 6, uu = idx & 63;
        float a = bfc1[uu];
        for (int k = 0; k < HID; ++k) a += h1_last[m*32+k] * Wfc1[uu*HID+k];
        zbuf[m*64+uu] = fmaxf(a, 0.f);
    }
    __syncthreads();
    #pragma unroll
    for (int rep = 0; rep < 2; ++rep) {
        int idx = tid + rep*256;          // 16*32
        int m = idx >> 5, v = idx & 31;
        float a = bfc2[v];
        for (int k = 0; k < 64; ++k) a += zbuf[m*64+k] * Wfc2[v*64+k];
        z2buf[m*32+v] = fmaxf(a, 0.f);
    }
    __syncthreads();
    if (tid < 16) {
        float a = bfc3[0];
        for (int k = 0; k < 32; ++k) a += z2buf[tid*32+k] * Wfc3[k];
        out[bbase + tid] = fsigmoid(a);
    }
}

extern "C" void kernel_launch(void* const* d_in, const int* in_sizes, int n_in,
                              void* d_out, int out_size, void* d_ws, size_t ws_size,
                              hipStream_t stream) {
    const float* x    = (const float*)d_in[0];
    const float* Wih0 = (const float*)d_in[1];
    const float* Whh0 = (const float*)d_in[2];
    const float* bih0 = (const float*)d_in[3];
    const float* bhh0 = (const float*)d_in[4];
    const float* Wih1 = (const float*)d_in[5];
    const float* Whh1 = (const float*)d_in[6];
    const float* bih1 = (const float*)d_in[7];
    const float* bhh1 = (const float*)d_in[8];
    const float* Wfc1 = (const float*)d_in[9];
    const float* bfc1 = (const float*)d_in[10];
    const float* Wfc2 = (const float*)d_in[11];
    const float* bfc2 = (const float*)d_in[12];
    const float* Wfc3 = (const float*)d_in[13];
    const float* bfc3 = (const float*)d_in[14];
    float* outp = (float*)d_out;

    hipLaunchKernelGGL(lstm_fused, dim3(512), dim3(256), 0, stream,
        x, Wih0, Whh0, bih0, bhh0, Wih1, Whh1, bih1, bhh1,
        Wfc1, bfc1, Wfc2, bfc2, Wfc3, bfc3, outp);
}

// Round 3
// 394.960 us; speedup vs baseline: 1.0559x; 1.0343x over previous
//
#include <hip/hip_runtime.h>

#define TT   256
#define HID  30
#define LOG2E 1.4426950408889634f
#define HS   56   // h-row stride in bf16: 112B = 7*16 -> b128-aligned, 2-way banks only

typedef __bf16 bf16x8_t __attribute__((ext_vector_type(8)));
typedef float  f32x4_t  __attribute__((ext_vector_type(4)));

__device__ __forceinline__ float fexp2(float x){
#if __has_builtin(__builtin_amdgcn_exp2f)
    return __builtin_amdgcn_exp2f(x);
#else
    return exp2f(x);
#endif
}
__device__ __forceinline__ float frcp(float x){
#if __has_builtin(__builtin_amdgcn_rcpf)
    return __builtin_amdgcn_rcpf(x);
#else
    return 1.f/x;
#endif
}
__device__ __forceinline__ float fsigmoid(float x){ return frcp(1.f + fexp2(-LOG2E*x)); }
__device__ __forceinline__ float ftanh_f(float x){ return 2.f*frcp(1.f + fexp2(-2.f*LOG2E*x)) - 1.f; }

// Skewed two-layer LSTM: iteration s computes layer0(t=s+1) AND layer1(t=s)
// concurrently (both consume h0(s); layer1 also consumes h1(s-1)).
// -> ONE barrier per iteration, 6 back-to-back MFMAs, 16 dense activation
// pairs per phase. Gate packing per wave: tile0={i|f}x8units, tile1={g|o};
// all 4 gates of a unit live in lanes n and n^8 -> shfl_xor(8) exchange.
__global__ __launch_bounds__(256, 2)
void lstm_fused(const float* __restrict__ x,
    const float* __restrict__ Wih0, const float* __restrict__ Whh0,
    const float* __restrict__ bih0, const float* __restrict__ bhh0,
    const float* __restrict__ Wih1, const float* __restrict__ Whh1,
    const float* __restrict__ bih1, const float* __restrict__ bhh1,
    const float* __restrict__ Wfc1, const float* __restrict__ bfc1,
    const float* __restrict__ Wfc2, const float* __restrict__ bfc2,
    const float* __restrict__ Wfc3, const float* __restrict__ bfc3,
    float* __restrict__ out)
{
    __shared__ __align__(16) __bf16 h0f[2][16][HS];  // [buf][m][k]; k=30,31: x0,x1(t)
    __shared__ __align__(16) __bf16 h1f[2][16][HS];
    __shared__ float h1_last[16*32];
    __shared__ float zbuf[16*64];
    __shared__ float z2buf[16*32];

    const int tid  = threadIdx.x;
    const int lane = tid & 63;
    const int wv   = tid >> 6;        // hidden quarter 0..3
    const int n    = lane & 15;
    const int q    = lane >> 4;
    const int nl   = n & 7;
    const int u    = wv*8 + nl;
    const int hi   = n >> 3;          // 0:{i,g} side  1:{f,o} side
    const bool colok = (u < HID);
    const int bbase = blockIdx.x * 16;

    const int uq  = colok ? u : 0;
    const int wr0 = (hi ? 1 : 0)*HID + uq;    // i/f row
    const int wr1 = (hi ? 3 : 2)*HID + uq;    // g/o row

    // ---- resident B-fragments: B[k=(q*8+j)][n] ----
    bf16x8_t fb0_hh0{}, fb1_hh0{}, fb0_ih1{}, fb1_ih1{}, fb0_hh1{}, fb1_hh1{};
    #pragma unroll
    for (int j = 0; j < 8; ++j) {
        int k = q*8 + j;
        float v00=0.f, v01=0.f, v10=0.f, v11=0.f, v20=0.f, v21=0.f;
        if (colok) {
            if (k < HID) {
                v00 = Whh0[wr0*HID + k];  v01 = Whh0[wr1*HID + k];
                v10 = Wih1[wr0*HID + k];  v11 = Wih1[wr1*HID + k];
                v20 = Whh1[wr0*HID + k];  v21 = Whh1[wr1*HID + k];
            } else {                    // k=30,31 -> x0,x1 cols of Wih0 (layer0 only)
                int xi = k - HID;
                v00 = Wih0[wr0*3 + xi];  v01 = Wih0[wr1*3 + xi];
            }
        }
        fb0_hh0[j]=(__bf16)v00; fb1_hh0[j]=(__bf16)v01;
        fb0_ih1[j]=(__bf16)v10; fb1_ih1[j]=(__bf16)v11;
        fb0_hh1[j]=(__bf16)v20; fb1_hh1[j]=(__bf16)v21;
    }
    float bias00=0.f, bias01=0.f, bias10=0.f, bias11=0.f, wx20=0.f, wx21=0.f;
    if (colok) {
        bias00 = bih0[wr0] + bhh0[wr0];  bias01 = bih0[wr1] + bhh0[wr1];
        bias10 = bih1[wr0] + bhh1[wr0];  bias11 = bih1[wr1] + bhh1[wr1];
        wx20 = Wih0[wr0*3 + 2];          wx21 = Wih0[wr1*3 + 2];
    }
    const f32x4_t bv00 = {bias00,bias00,bias00,bias00};
    const f32x4_t bv01 = {bias01,bias01,bias01,bias01};
    const f32x4_t bv10 = {bias10,bias10,bias10,bias10};
    const f32x4_t bv11 = {bias11,bias11,bias11,bias11};

    const float mco1 = (hi==0) ? (-2.f*LOG2E) : (-LOG2E);   // tile1: g=tanh | o=sigm
    const float aco1 = (hi==0) ? 2.f : 1.f;
    const float bco1 = (hi==0) ? -1.f : 0.f;

    f32x4_t c0 = {0.f,0.f,0.f,0.f}, c1 = {0.f,0.f,0.f,0.f};

    for (int i = tid; i < 2*16*HS; i += 256) {
        (&h0f[0][0][0])[i] = (__bf16)0.f;
        (&h1f[0][0][0])[i] = (__bf16)0.f;
    }
    __syncthreads();
    if (tid < 32) {     // x0,x1(t=0) into prologue read-buffer h0f[1]
        int m = tid >> 1, cc = tid & 1;
        h0f[1][m][30+cc] = (__bf16)x[(size_t)(bbase+m)*(TT*3) + cc];
    }
    __syncthreads();

    // x2(0) now; strength-reduced prefetch pointers at t=1
    f32x4_t x2;
    const float* xr0; const float* xr1; const float* xr2; const float* xr3;
    {
        const float* b0 = x + (size_t)(bbase + q*4 + 0)*(TT*3);
        const float* b1 = x + (size_t)(bbase + q*4 + 1)*(TT*3);
        const float* b2 = x + (size_t)(bbase + q*4 + 2)*(TT*3);
        const float* b3 = x + (size_t)(bbase + q*4 + 3)*(TT*3);
        x2[0]=b0[2]; x2[1]=b1[2]; x2[2]=b2[2]; x2[3]=b3[2];
        xr0=b0+5; xr1=b1+5; xr2=b2+5; xr3=b3+5;   // t=1, comp 2
    }
    const float* px01 = x + (size_t)(bbase + (tid>>1))*(TT*3) + 3 + (tid&1);

    #pragma unroll 1
    for (int s = -1; s < TT; ++s) {
        const int rb = s & 1, wb = rb ^ 1;

        // ---- all 6 MFMAs up front (layer0 t=s+1, layer1 t=s) ----
        bf16x8_t A0 = *(const bf16x8_t*)(&h0f[rb][n][q*8]);  // h0(s) + x0,x1(s+1)
        bf16x8_t A2 = *(const bf16x8_t*)(&h1f[rb][n][q*8]);  // h1(s-1)
        f32x4_t acc0 = __builtin_amdgcn_mfma_f32_16x16x32_bf16(A0, fb0_hh0, bv00, 0,0,0);
        f32x4_t acc1 = __builtin_amdgcn_mfma_f32_16x16x32_bf16(A0, fb1_hh0, bv01, 0,0,0);
        f32x4_t d0   = __builtin_amdgcn_mfma_f32_16x16x32_bf16(A0, fb0_ih1, bv10, 0,0,0);
        d0           = __builtin_amdgcn_mfma_f32_16x16x32_bf16(A2, fb0_hh1, d0,   0,0,0);
        f32x4_t d1   = __builtin_amdgcn_mfma_f32_16x16x32_bf16(A0, fb1_ih1, bv11, 0,0,0);
        d1           = __builtin_amdgcn_mfma_f32_16x16x32_bf16(A2, fb1_hh1, d1,   0,0,0);

        // ---- prefetch x(s+2) while MFMAs are in flight ----
        f32x4_t x2n;
        x2n[0]=*xr0; x2n[1]=*xr1; x2n[2]=*xr2; x2n[3]=*xr3;
        float x01v = 0.f;
        if (tid < 32) x01v = *px01;
        if (s < TT-3) { xr0+=3; xr1+=3; xr2+=3; xr3+=3; px01+=3; }
        if (tid < 32) h0f[wb][tid>>1][30+(tid&1)] = (__bf16)x01v;

        // ---- layer 0 activations / state ----
        f32x4_t ga0, ga1, p;
        #pragma unroll
        for (int r = 0; r < 4; ++r) { acc0[r] += x2[r]*wx20; acc1[r] += x2[r]*wx21; }
        #pragma unroll
        for (int r = 0; r < 4; ++r) {
            ga0[r] = frcp(1.f + fexp2(acc0[r]*(-LOG2E)));          // i | f
            ga1[r] = aco1*frcp(1.f + fexp2(acc1[r]*mco1)) + bco1;  // g | o
            p[r]   = ga0[r]*ga1[r];
        }
        #pragma unroll
        for (int r = 0; r < 4; ++r) p[r] = __shfl_xor(p[r], 8, 64);
        #pragma unroll
        for (int r = 0; r < 4; ++r) c0[r] = ga0[r]*c0[r] + p[r];   // valid on hi lanes
        if (hi && colok) {
            #pragma unroll
            for (int r = 0; r < 4; ++r)
                h0f[wb][q*4+r][u] = (__bf16)(ga1[r]*ftanh_f(c0[r]));
        }

        // ---- layer 1 activations / state (discard at s==-1) ----
        f32x4_t gb0, gb1, pb;
        #pragma unroll
        for (int r = 0; r < 4; ++r) {
            gb0[r] = frcp(1.f + fexp2(d0[r]*(-LOG2E)));
            gb1[r] = aco1*frcp(1.f + fexp2(d1[r]*mco1)) + bco1;
            pb[r]  = gb0[r]*gb1[r];
        }
        #pragma unroll
        for (int r = 0; r < 4; ++r) pb[r] = __shfl_xor(pb[r], 8, 64);
        if (s >= 0) {
            #pragma unroll
            for (int r = 0; r < 4; ++r) c1[r] = gb0[r]*c1[r] + pb[r];
            if (hi && colok) {
                #pragma unroll
                for (int r = 0; r < 4; ++r) {
                    float h1v = gb1[r]*ftanh_f(c1[r]);
                    h1f[wb][q*4+r][u] = (__bf16)h1v;
                    if (s == TT-1) h1_last[(q*4+r)*32 + u] = h1v;
                }
            }
        }
        x2 = x2n;
        __syncthreads();   // the ONLY barrier per iteration
    }

    // ---- FC head ----
    #pragma unroll
    for (int rep = 0; rep < 4; ++rep) {
        int idx = tid + rep*256;          // 16*64
        int m = idx >> 6, uu = idx & 63;
        float a = bfc1[uu];
        for (int k = 0; k < HID; ++k) a += h1_last[m*32+k] * Wfc1[uu*HID+k];
        zbuf[m*64+uu] = fmaxf(a, 0.f);
    }
    __syncthreads();
    #pragma unroll
    for (int rep = 0; rep < 2; ++rep) {
        int idx = tid + rep*256;          // 16*32
        int m = idx >> 5, v = idx & 31;
        float a = bfc2[v];
        for (int k = 0; k < 64; ++k) a += zbuf[m*64+k] * Wfc2[v*64+k];
        z2buf[m*32+v] = fmaxf(a, 0.f);
    }
    __syncthreads();
    if (tid < 16) {
        float a = bfc3[0];
        for (int k = 0; k < 32; ++k) a += z2buf[tid*32+k] * Wfc3[k];
        out[bbase + tid] = fsigmoid(a);
    }
}

extern "C" void kernel_launch(void* const* d_in, const int* in_sizes, int n_in,
                              void* d_out, int out_size, void* d_ws, size_t ws_size,
                              hipStream_t stream) {
    const float* x    = (const float*)d_in[0];
    const float* Wih0 = (const float*)d_in[1];
    const float* Whh0 = (const float*)d_in[2];
    const float* bih0 = (const float*)d_in[3];
    const float* bhh0 = (const float*)d_in[4];
    const float* Wih1 = (const float*)d_in[5];
    const float* Whh1 = (const float*)d_in[6];
    const float* bih1 = (const float*)d_in[7];
    const float* bhh1 = (const float*)d_in[8];
    const float* Wfc1 = (const float*)d_in[9];
    const float* bfc1 = (const float*)d_in[10];
    const float* Wfc2 = (const float*)d_in[11];
    const float* bfc2 = (const float*)d_in[12];
    const float* Wfc3 = (const float*)d_in[13];
    const float* bfc3 = (const float*)d_in[14];
    float* outp = (float*)d_out;

    hipLaunchKernelGGL(lstm_fused, dim3(512), dim3(256), 0, stream,
        x, Wih0, Whh0, bih0, bhh0, Wih1, Whh1, bih1, bhh1,
        Wfc1, bfc1, Wfc2, bfc2, Wfc3, bfc3, outp);
}

// Round 4
// 355.079 us; speedup vs baseline: 1.1744x; 1.1123x over previous
//
#include <hip/hip_runtime.h>

#define TT   256
#define HID  30
#define LOG2E 1.4426950408889634f
#define HS   56   // h-row stride in bf16: 112B -> b128 reads are 2-way (free)

typedef __bf16 bf16x8_t __attribute__((ext_vector_type(8)));
typedef float  f32x4_t  __attribute__((ext_vector_type(4)));

__device__ __forceinline__ float fexp2(float x){
#if __has_builtin(__builtin_amdgcn_exp2f)
    return __builtin_amdgcn_exp2f(x);
#else
    return exp2f(x);
#endif
}
__device__ __forceinline__ float frcp(float x){
#if __has_builtin(__builtin_amdgcn_rcpf)
    return __builtin_amdgcn_rcpf(x);
#else
    return 1.f/x;
#endif
}
__device__ __forceinline__ float fsigmoid(float x){ return frcp(1.f + fexp2(-LOG2E*x)); }
__device__ __forceinline__ float ftanh_f(float x){ return 2.f*frcp(1.f + fexp2(-2.f*LOG2E*x)) - 1.f; }

// Wave-specialized skewed 2-layer LSTM. Block = 512 threads = 8 waves,
// owns 16 batch rows. Waves 0-3 (group A) compute layer0(t=s+1); waves 4-7
// (group B) compute layer1(t=s) — independent within an iteration, so one
// barrier/step. Per-group gate packing (R3-validated): wave wv owns units
// [8wv, 8wv+8), tile0={i|f}x8u, tile1={g|o}x8u; all 4 gates of a unit in
// lanes n / n^8 -> single shfl_xor(8). h exchanged via double-buffered LDS
// (A-frag layout); x0,x1 folded into k-slots 30/31 of h0's A-fragment.
__global__ __launch_bounds__(512, 4)
void lstm_fused(const float* __restrict__ x,
    const float* __restrict__ Wih0, const float* __restrict__ Whh0,
    const float* __restrict__ bih0, const float* __restrict__ bhh0,
    const float* __restrict__ Wih1, const float* __restrict__ Whh1,
    const float* __restrict__ bih1, const float* __restrict__ bhh1,
    const float* __restrict__ Wfc1, const float* __restrict__ bfc1,
    const float* __restrict__ Wfc2, const float* __restrict__ bfc2,
    const float* __restrict__ Wfc3, const float* __restrict__ bfc3,
    float* __restrict__ out)
{
    __shared__ __align__(16) __bf16 h0f[2][16][HS];  // [buf][m][k]; k=30,31: x0,x1
    __shared__ __align__(16) __bf16 h1f[2][16][HS];
    __shared__ float h1_last[16*32];
    __shared__ float zbuf[16*64];
    __shared__ float z2buf[16*32];

    const int tid  = threadIdx.x;
    const int lane = tid & 63;
    const int wvf  = tid >> 6;         // 0..7
    const bool grpA = (wvf < 4);
    const int wv   = wvf & 3;          // unit quarter within group
    const int n    = lane & 15;
    const int q    = lane >> 4;
    const int nl   = n & 7;
    const int u    = wv*8 + nl;        // hidden unit
    const int hi   = n >> 3;           // 0:{i,g} 1:{f,o}
    const bool colok = (u < HID);
    const int bbase = blockIdx.x * 16;

    const int uq  = colok ? u : 0;
    const int wr0 = (hi ? 1 : 0)*HID + uq;    // i/f weight row
    const int wr1 = (hi ? 3 : 2)*HID + uq;    // g/o weight row

    // ---- group-specialized resident B-fragments: B[k=(q*8+j)][n] ----
    // grpA: fbA/fbB = Whh0 tiles (k30/31 = Wih0 cols 0,1).  fbC/fbD unused.
    // grpB: fbA/fbB = Wih1 tiles, fbC/fbD = Whh1 tiles.
    bf16x8_t fbA{}, fbB{}, fbC{}, fbD{};
    float b0=0.f, b1=0.f, wx20=0.f, wx21=0.f;
    if (grpA) {
        #pragma unroll
        for (int j = 0; j < 8; ++j) {
            int k = q*8 + j;
            float v0=0.f, v1=0.f;
            if (colok) {
                if (k < HID) { v0 = Whh0[wr0*HID+k];      v1 = Whh0[wr1*HID+k]; }
                else         { v0 = Wih0[wr0*3+(k-HID)];  v1 = Wih0[wr1*3+(k-HID)]; }
            }
            fbA[j]=(__bf16)v0; fbB[j]=(__bf16)v1;
        }
        if (colok) {
            b0 = bih0[wr0] + bhh0[wr0];
            b1 = bih0[wr1] + bhh0[wr1];
            wx20 = Wih0[wr0*3+2];  wx21 = Wih0[wr1*3+2];
        }
    } else {
        #pragma unroll
        for (int j = 0; j < 8; ++j) {
            int k = q*8 + j;
            float v0=0.f, v1=0.f, v2=0.f, v3=0.f;
            if (colok && k < HID) {
                v0 = Wih1[wr0*HID+k];  v1 = Wih1[wr1*HID+k];
                v2 = Whh1[wr0*HID+k];  v3 = Whh1[wr1*HID+k];
            }
            fbA[j]=(__bf16)v0; fbB[j]=(__bf16)v1;
            fbC[j]=(__bf16)v2; fbD[j]=(__bf16)v3;
        }
        if (colok) {
            b0 = bih1[wr0] + bhh1[wr0];
            b1 = bih1[wr1] + bhh1[wr1];
        }
    }
    const f32x4_t bv0 = {b0,b0,b0,b0};
    const f32x4_t bv1 = {b1,b1,b1,b1};
    const float mco1 = (hi==0) ? (-2.f*LOG2E) : (-LOG2E);  // tile1: g=tanh | o=sigm
    const float aco1 = (hi==0) ? 2.f : 1.f;
    const float bco1 = (hi==0) ? -1.f : 0.f;
    const bool wrh = hi && colok;

    f32x4_t cst = {0.f,0.f,0.f,0.f};   // c0 (grpA) or c1 (grpB)

    for (int i = tid; i < 2*16*HS; i += 512) {
        (&h0f[0][0][0])[i] = (__bf16)0.f;
        (&h1f[0][0][0])[i] = (__bf16)0.f;
    }
    __syncthreads();
    if (tid < 32) {    // x0,x1(t=0) into prologue read-buffer h0f[1]
        int m = tid >> 1, cc = tid & 1;
        h0f[1][m][30+cc] = (__bf16)x[(size_t)(bbase+m)*(TT*3) + cc];
    }
    __syncthreads();

    // x pipeline (group A only): x2 holds x2(s+1); xr/px01 point at t=1
    f32x4_t x2 = {0.f,0.f,0.f,0.f};
    const float *xr0=nullptr,*xr1=nullptr,*xr2=nullptr,*xr3=nullptr,*px01=nullptr;
    if (grpA) {
        const float* c0p = x + (size_t)(bbase + q*4 + 0)*(TT*3);
        const float* c1p = x + (size_t)(bbase + q*4 + 1)*(TT*3);
        const float* c2p = x + (size_t)(bbase + q*4 + 2)*(TT*3);
        const float* c3p = x + (size_t)(bbase + q*4 + 3)*(TT*3);
        x2[0]=c0p[2]; x2[1]=c1p[2]; x2[2]=c2p[2]; x2[3]=c3p[2];
        xr0=c0p+5; xr1=c1p+5; xr2=c2p+5; xr3=c3p+5;
        px01 = x + (size_t)(bbase + (tid>>1))*(TT*3) + 3 + (tid&1);
    }

    #pragma unroll 1
    for (int s = -1; s < TT; ++s) {
        const int rb = s & 1, wb = rb ^ 1;
        if (grpA) {
            // ---- layer 0, t = s+1 ----
            bf16x8_t A0 = *(const bf16x8_t*)(&h0f[rb][n][q*8]);
            f32x4_t a0 = __builtin_amdgcn_mfma_f32_16x16x32_bf16(A0, fbA, bv0, 0,0,0);
            f32x4_t a1 = __builtin_amdgcn_mfma_f32_16x16x32_bf16(A0, fbB, bv1, 0,0,0);
            // prefetch x(s+2) while MFMAs are in flight
            f32x4_t x2n;
            x2n[0]=*xr0; x2n[1]=*xr1; x2n[2]=*xr2; x2n[3]=*xr3;
            float x01v = 0.f;
            if (tid < 32) x01v = *px01;
            if (s < TT-3) { xr0+=3; xr1+=3; xr2+=3; xr3+=3; px01+=3; }
            if (tid < 32) h0f[wb][tid>>1][30+(tid&1)] = (__bf16)x01v;

            f32x4_t g0, g1, p;
            #pragma unroll
            for (int r=0;r<4;++r){ a0[r] += x2[r]*wx20; a1[r] += x2[r]*wx21; }
            #pragma unroll
            for (int r=0;r<4;++r){
                g0[r] = frcp(1.f + fexp2(a0[r]*(-LOG2E)));          // i | f
                g1[r] = aco1*frcp(1.f + fexp2(a1[r]*mco1)) + bco1;  // g | o
                p[r]  = g0[r]*g1[r];
            }
            #pragma unroll
            for (int r=0;r<4;++r) p[r] = __shfl_xor(p[r], 8, 64);
            #pragma unroll
            for (int r=0;r<4;++r) cst[r] = g0[r]*cst[r] + p[r];
            if (wrh) {
                #pragma unroll
                for (int r=0;r<4;++r)
                    h0f[wb][q*4+r][u] = (__bf16)(g1[r]*ftanh_f(cst[r]));
            }
            x2 = x2n;
        } else {
            // ---- layer 1, t = s ----
            bf16x8_t A1 = *(const bf16x8_t*)(&h0f[rb][n][q*8]);  // h0(s)
            bf16x8_t A2 = *(const bf16x8_t*)(&h1f[rb][n][q*8]);  // h1(s-1)
            f32x4_t d0 = __builtin_amdgcn_mfma_f32_16x16x32_bf16(A1, fbA, bv0, 0,0,0);
            d0         = __builtin_amdgcn_mfma_f32_16x16x32_bf16(A2, fbC, d0,  0,0,0);
            f32x4_t d1 = __builtin_amdgcn_mfma_f32_16x16x32_bf16(A1, fbB, bv1, 0,0,0);
            d1         = __builtin_amdgcn_mfma_f32_16x16x32_bf16(A2, fbD, d1,  0,0,0);
            f32x4_t g0, g1, p;
            #pragma unroll
            for (int r=0;r<4;++r){
                g0[r] = frcp(1.f + fexp2(d0[r]*(-LOG2E)));
                g1[r] = aco1*frcp(1.f + fexp2(d1[r]*mco1)) + bco1;
                p[r]  = g0[r]*g1[r];
            }
            #pragma unroll
            for (int r=0;r<4;++r) p[r] = __shfl_xor(p[r], 8, 64);
            if (s >= 0) {
                #pragma unroll
                for (int r=0;r<4;++r) cst[r] = g0[r]*cst[r] + p[r];
                if (wrh) {
                    #pragma unroll
                    for (int r=0;r<4;++r) {
                        float h1v = g1[r]*ftanh_f(cst[r]);
                        h1f[wb][q*4+r][u] = (__bf16)h1v;
                        if (s == TT-1) h1_last[(q*4+r)*32 + u] = h1v;
                    }
                }
            }
        }
        __syncthreads();   // the only barrier per step
    }

    // ---- FC head (512 threads) ----
    #pragma unroll
    for (int rep = 0; rep < 2; ++rep) {
        int idx = tid + rep*512;          // 16*64 outputs
        int m = idx >> 6, uu = idx & 63;
        float a = bfc1[uu];
        for (int k = 0; k < HID; ++k) a += h1_last[m*32+k] * Wfc1[uu*HID+k];
        zbuf[m*64+uu] = fmaxf(a, 0.f);
    }
    __syncthreads();
    {
        int m = tid >> 5, v = tid & 31;   // 16*32 outputs
        float a = bfc2[v];
        for (int k = 0; k < 64; ++k) a += zbuf[m*64+k] * Wfc2[v*64+k];
        z2buf[m*32+v] = fmaxf(a, 0.f);
    }
    __syncthreads();
    if (tid < 16) {
        float a = bfc3[0];
        for (int k = 0; k < 32; ++k) a += z2buf[tid*32+k] * Wfc3[k];
        out[bbase + tid] = fsigmoid(a);
    }
}

extern "C" void kernel_launch(void* const* d_in, const int* in_sizes, int n_in,
                              void* d_out, int out_size, void* d_ws, size_t ws_size,
                              hipStream_t stream) {
    const float* x    = (const float*)d_in[0];
    const float* Wih0 = (const float*)d_in[1];
    const float* Whh0 = (const float*)d_in[2];
    const float* bih0 = (const float*)d_in[3];
    const float* bhh0 = (const float*)d_in[4];
    const float* Wih1 = (const float*)d_in[5];
    const float* Whh1 = (const float*)d_in[6];
    const float* bih1 = (const float*)d_in[7];
    const float* bhh1 = (const float*)d_in[8];
    const float* Wfc1 = (const float*)d_in[9];
    const float* bfc1 = (const float*)d_in[10];
    const float* Wfc2 = (const float*)d_in[11];
    const float* bfc2 = (const float*)d_in[12];
    const float* Wfc3 = (const float*)d_in[13];
    const float* bfc3 = (const float*)d_in[14];
    float* outp = (float*)d_out;

    hipLaunchKernelGGL(lstm_fused, dim3(512), dim3(512), 0, stream,
        x, Wih0, Whh0, bih0, bhh0, Wih1, Whh1, bih1, bhh1,
        Wfc1, bfc1, Wfc2, bfc2, Wfc3, bfc3, outp);
}

// Round 5
// 329.898 us; speedup vs baseline: 1.2641x; 1.0763x over previous
//
#include <hip/hip_runtime.h>

#define TT   256
#define HID  30
#define LOG2E 1.4426950408889634f
#define HS   56   // h-row stride in bf16: 112B -> b128 reads 2-way (free)

typedef __bf16 bf16x8_t __attribute__((ext_vector_type(8)));
typedef float  f32x4_t  __attribute__((ext_vector_type(4)));

__device__ __forceinline__ float fexp2(float x){
#if __has_builtin(__builtin_amdgcn_exp2f)
    return __builtin_amdgcn_exp2f(x);
#else
    return exp2f(x);
#endif
}
__device__ __forceinline__ float frcp(float x){
#if __has_builtin(__builtin_amdgcn_rcpf)
    return __builtin_amdgcn_rcpf(x);
#else
    return 1.f/x;
#endif
}
__device__ __forceinline__ float fsigmoid(float x){ return frcp(1.f + fexp2(-LOG2E*x)); }
__device__ __forceinline__ float ftanh_f(float x){ return 2.f*frcp(1.f + fexp2(-2.f*LOG2E*x)) - 1.f; }
__device__ __forceinline__ f32x4_t exp4(f32x4_t v){
    f32x4_t e; e[0]=fexp2(v[0]); e[1]=fexp2(v[1]); e[2]=fexp2(v[2]); e[3]=fexp2(v[3]); return e;
}
__device__ __forceinline__ f32x4_t rcp4(f32x4_t v){
    f32x4_t r; r[0]=frcp(v[0]); r[1]=frcp(v[1]); r[2]=frcp(v[2]); r[3]=frcp(v[3]); return r;
}

// Wave-specialized skewed 2-layer LSTM (R4 structure) + issue-count diet:
//  - tanh epilogue split hi/lo lanes via shfl (4 tanh sets -> 2)
//  - x loads: SGPR base (SALU bump) + fixed VGPR offsets -> 0 VALU addressing
//  - 2x unrolled step macro with literal buffer indices -> LDS addrs fold to
//    instruction immediates
//  - activations as ext-vector ops -> v_pk_* packed fp32 where possible
__global__ __launch_bounds__(512, 4)
void lstm_fused(const float* __restrict__ x,
    const float* __restrict__ Wih0, const float* __restrict__ Whh0,
    const float* __restrict__ bih0, const float* __restrict__ bhh0,
    const float* __restrict__ Wih1, const float* __restrict__ Whh1,
    const float* __restrict__ bih1, const float* __restrict__ bhh1,
    const float* __restrict__ Wfc1, const float* __restrict__ bfc1,
    const float* __restrict__ Wfc2, const float* __restrict__ bfc2,
    const float* __restrict__ Wfc3, const float* __restrict__ bfc3,
    float* __restrict__ out)
{
    __shared__ __align__(16) __bf16 h0f[2][16][HS];  // [buf][m][k]; k=30,31: x0,x1
    __shared__ __align__(16) __bf16 h1f[2][16][HS];
    __shared__ float h1_last[16*32];
    __shared__ float zbuf[16*64];
    __shared__ float z2buf[16*32];

    const int tid  = threadIdx.x;
    const int lane = tid & 63;
    const int wvf  = tid >> 6;         // 0..7
    const bool grpA = (wvf < 4);
    const int wv   = wvf & 3;
    const int n    = lane & 15;
    const int q    = lane >> 4;
    const int nl   = n & 7;
    const int u    = wv*8 + nl;        // hidden unit
    const int hi   = n >> 3;           // 0:{i,g} 1:{f,o}
    const bool colok = (u < HID);
    const int bbase = blockIdx.x * 16;

    const int uq  = colok ? u : 0;
    const int wr0 = (hi ? 1 : 0)*HID + uq;    // i/f row
    const int wr1 = (hi ? 3 : 2)*HID + uq;    // g/o row

    // ---- group-specialized resident B-fragments ----
    bf16x8_t fbA{}, fbB{}, fbC{}, fbD{};
    float b0=0.f, b1=0.f, wx20=0.f, wx21=0.f;
    if (grpA) {
        #pragma unroll
        for (int j = 0; j < 8; ++j) {
            int k = q*8 + j;
            float v0=0.f, v1=0.f;
            if (colok) {
                if (k < HID) { v0 = Whh0[wr0*HID+k];      v1 = Whh0[wr1*HID+k]; }
                else         { v0 = Wih0[wr0*3+(k-HID)];  v1 = Wih0[wr1*3+(k-HID)]; }
            }
            fbA[j]=(__bf16)v0; fbB[j]=(__bf16)v1;
        }
        if (colok) {
            b0 = bih0[wr0] + bhh0[wr0];
            b1 = bih0[wr1] + bhh0[wr1];
            wx20 = Wih0[wr0*3+2];  wx21 = Wih0[wr1*3+2];
        }
    } else {
        #pragma unroll
        for (int j = 0; j < 8; ++j) {
            int k = q*8 + j;
            float v0=0.f, v1=0.f, v2=0.f, v3=0.f;
            if (colok && k < HID) {
                v0 = Wih1[wr0*HID+k];  v1 = Wih1[wr1*HID+k];
                v2 = Whh1[wr0*HID+k];  v3 = Whh1[wr1*HID+k];
            }
            fbA[j]=(__bf16)v0; fbB[j]=(__bf16)v1;
            fbC[j]=(__bf16)v2; fbD[j]=(__bf16)v3;
        }
        if (colok) {
            b0 = bih1[wr0] + bhh1[wr0];
            b1 = bih1[wr1] + bhh1[wr1];
        }
    }
    const f32x4_t bv0 = {b0,b0,b0,b0};
    const f32x4_t bv1 = {b1,b1,b1,b1};
    const float mco1 = (hi==0) ? (-2.f*LOG2E) : (-LOG2E);  // tile1: g=tanh | o=sigm
    const float aco1 = (hi==0) ? 2.f : 1.f;
    const float bco1 = (hi==0) ? -1.f : 0.f;

    f32x4_t cst = {0.f,0.f,0.f,0.f};

    for (int i = tid; i < 2*16*HS; i += 512) {
        (&h0f[0][0][0])[i] = (__bf16)0.f;
        (&h1f[0][0][0])[i] = (__bf16)0.f;
    }
    __syncthreads();
    if (tid < 32) {    // x0,x1(t=0) into prologue read-buffer h0f[1]
        int m = tid >> 1, cc = tid & 1;
        h0f[1][m][30+cc] = (__bf16)x[(size_t)(bbase+m)*(TT*3) + cc];
    }
    __syncthreads();

    // x addressing: uniform SGPR base xB (+3*t per step, SALU) + fixed VGPR offsets
    const float* xB = x + (size_t)bbase*(TT*3);
    const int xo2  = (q*4)*(TT*3) + 2;           // + r*TT*3 for r=0..3
    const int xo01 = (tid>>1)*(TT*3) + (tid&1);
    f32x4_t x2 = {0.f,0.f,0.f,0.f};
    if (grpA) {   // x2(t=0)
        x2[0]=xB[xo2]; x2[1]=xB[xo2+TT*3]; x2[2]=xB[xo2+2*TT*3]; x2[3]=xB[xo2+3*TT*3];
    }

#define STEP(S, RB, WB, FIRST) do {                                            \
    if (grpA) {                                                                \
        bf16x8_t A0 = *(const bf16x8_t*)(&h0f[RB][n][q*8]);                    \
        f32x4_t bx0 = bv0 + x2*wx20;                                           \
        f32x4_t bx1 = bv1 + x2*wx21;                                           \
        f32x4_t a0 = __builtin_amdgcn_mfma_f32_16x16x32_bf16(A0, fbA, bx0, 0,0,0); \
        f32x4_t a1 = __builtin_amdgcn_mfma_f32_16x16x32_bf16(A0, fbB, bx1, 0,0,0); \
        const int tpre = ((S)+2 < TT) ? (S)+2 : TT-1;                          \
        const float* xs = xB + 3*tpre;                                         \
        f32x4_t x2n;                                                           \
        x2n[0]=xs[xo2]; x2n[1]=xs[xo2+TT*3];                                   \
        x2n[2]=xs[xo2+2*TT*3]; x2n[3]=xs[xo2+3*TT*3];                          \
        float x01v = 0.f;                                                      \
        if (tid < 32) x01v = xs[xo01];                                         \
        f32x4_t g0 = rcp4(exp4(a0*(-LOG2E)) + 1.f);                            \
        f32x4_t g1 = rcp4(exp4(a1*mco1) + 1.f)*aco1 + bco1;                    \
        f32x4_t p  = g0*g1;                                                    \
        p[0]=__shfl_xor(p[0],8,64); p[1]=__shfl_xor(p[1],8,64);                \
        p[2]=__shfl_xor(p[2],8,64); p[3]=__shfl_xor(p[3],8,64);                \
        cst = g0*cst + p;                                                      \
        float cA=cst[0], oA=g1[0], cB=cst[1], oB=g1[1];                        \
        float c2=__shfl_xor(cst[2],8,64), c3=__shfl_xor(cst[3],8,64);          \
        float o2=__shfl_xor(g1[2],8,64),  o3=__shfl_xor(g1[3],8,64);           \
        if (!hi) { cA=c2; oA=o2; cB=c3; oB=o3; }                               \
        float hA = oA*ftanh_f(cA);                                             \
        float hB = oB*ftanh_f(cB);                                             \
        const int row = q*4 + (hi ? 0 : 2);                                    \
        if (colok) {                                                           \
            h0f[WB][row][u]   = (__bf16)hA;                                    \
            h0f[WB][row+1][u] = (__bf16)hB;                                    \
        }                                                                      \
        if (tid < 32) h0f[WB][tid>>1][30+(tid&1)] = (__bf16)x01v;              \
        x2 = x2n;                                                              \
    } else if (!(FIRST)) {                                                     \
        bf16x8_t A1 = *(const bf16x8_t*)(&h0f[RB][n][q*8]);                    \
        bf16x8_t A2 = *(const bf16x8_t*)(&h1f[RB][n][q*8]);                    \
        f32x4_t d0 = __builtin_amdgcn_mfma_f32_16x16x32_bf16(A2, fbC, bv0, 0,0,0); \
        d0         = __builtin_amdgcn_mfma_f32_16x16x32_bf16(A1, fbA, d0,  0,0,0); \
        f32x4_t d1 = __builtin_amdgcn_mfma_f32_16x16x32_bf16(A2, fbD, bv1, 0,0,0); \
        d1         = __builtin_amdgcn_mfma_f32_16x16x32_bf16(A1, fbB, d1,  0,0,0); \
        f32x4_t g0 = rcp4(exp4(d0*(-LOG2E)) + 1.f);                            \
        f32x4_t g1 = rcp4(exp4(d1*mco1) + 1.f)*aco1 + bco1;                    \
        f32x4_t p  = g0*g1;                                                    \
        p[0]=__shfl_xor(p[0],8,64); p[1]=__shfl_xor(p[1],8,64);                \
        p[2]=__shfl_xor(p[2],8,64); p[3]=__shfl_xor(p[3],8,64);                \
        cst = g0*cst + p;                                                      \
        float cA=cst[0], oA=g1[0], cB=cst[1], oB=g1[1];                        \
        float c2=__shfl_xor(cst[2],8,64), c3=__shfl_xor(cst[3],8,64);          \
        float o2=__shfl_xor(g1[2],8,64),  o3=__shfl_xor(g1[3],8,64);           \
        if (!hi) { cA=c2; oA=o2; cB=c3; oB=o3; }                               \
        float hA = oA*ftanh_f(cA);                                             \
        float hB = oB*ftanh_f(cB);                                             \
        const int row = q*4 + (hi ? 0 : 2);                                    \
        if (colok) {                                                           \
            h1f[WB][row][u]   = (__bf16)hA;                                    \
            h1f[WB][row+1][u] = (__bf16)hB;                                    \
            if ((S) == TT-1) {                                                 \
                h1_last[row*32+u]     = hA;                                    \
                h1_last[(row+1)*32+u] = hB;                                    \
            }                                                                  \
        }                                                                      \
    }                                                                          \
    __syncthreads();                                                           \
} while (0)

    STEP(-1, 1, 0, 1);          // prologue: layer0 t=0 only
    #pragma unroll 1
    for (int s = 0; s < TT; s += 2) {
        STEP(s,   0, 1, 0);
        STEP(s+1, 1, 0, 0);
    }
#undef STEP

    // ---- FC head (512 threads) ----
    #pragma unroll
    for (int rep = 0; rep < 2; ++rep) {
        int idx = tid + rep*512;          // 16*64 outputs
        int m = idx >> 6, uu = idx & 63;
        float a = bfc1[uu];
        for (int k = 0; k < HID; ++k) a += h1_last[m*32+k] * Wfc1[uu*HID+k];
        zbuf[m*64+uu] = fmaxf(a, 0.f);
    }
    __syncthreads();
    {
        int m = tid >> 5, v = tid & 31;   // 16*32 outputs
        float a = bfc2[v];
        for (int k = 0; k < 64; ++k) a += zbuf[m*64+k] * Wfc2[v*64+k];
        z2buf[m*32+v] = fmaxf(a, 0.f);
    }
    __syncthreads();
    if (tid < 16) {
        float a = bfc3[0];
        for (int k = 0; k < 32; ++k) a += z2buf[tid*32+k] * Wfc3[k];
        out[bbase + tid] = fsigmoid(a);
    }
}

extern "C" void kernel_launch(void* const* d_in, const int* in_sizes, int n_in,
                              void* d_out, int out_size, void* d_ws, size_t ws_size,
                              hipStream_t stream) {
    const float* x    = (const float*)d_in[0];
    const float* Wih0 = (const float*)d_in[1];
    const float* Whh0 = (const float*)d_in[2];
    const float* bih0 = (const float*)d_in[3];
    const float* bhh0 = (const float*)d_in[4];
    const float* Wih1 = (const float*)d_in[5];
    const float* Whh1 = (const float*)d_in[6];
    const float* bih1 = (const float*)d_in[7];
    const float* bhh1 = (const float*)d_in[8];
    const float* Wfc1 = (const float*)d_in[9];
    const float* bfc1 = (const float*)d_in[10];
    const float* Wfc2 = (const float*)d_in[11];
    const float* bfc2 = (const float*)d_in[12];
    const float* Wfc3 = (const float*)d_in[13];
    const float* bfc3 = (const float*)d_in[14];
    float* outp = (float*)d_out;

    hipLaunchKernelGGL(lstm_fused, dim3(512), dim3(512), 0, stream,
        x, Wih0, Whh0, bih0, bhh0, Wih1, Whh1, bih1, bhh1,
        Wfc1, bfc1, Wfc2, bfc2, Wfc3, bfc3, outp);
}